// Round 9
// baseline (119.012 us; speedup 1.0000x reference)
//
#include <hip/hip_runtime.h>
#include <math.h>

#define NJ 8         // odd powers x^1..x^15
#define DEG 15
#define X0f 3.0f
#define NB 4         // batch rows per block
#define NT 768       // threads per block (12 waves)

struct Poly { float c[NJ]; };

#define FMA4(A,S,W) do { (A).x = fmaf((S),(W).x,(A).x); (A).y = fmaf((S),(W).y,(A).y); \
                         (A).z = fmaf((S),(W).z,(A).z); (A).w = fmaf((S),(W).w,(A).w); } while(0)

// ---------------- K0: repack weights ----------------
// WcT[i][m 0..463][32]  (m = seg*152+e', zero pads)
// W1T[m 0..455][128]
// Wt0[304][152], Wt1[76][152], Wt2[36][152]  (d-major, e-padded, zero pads)
__global__ __launch_bounds__(256) void k_repack(
    const float* __restrict__ Wc, const float* __restrict__ W1,
    const float* __restrict__ eW0, const float* __restrict__ eW1, const float* __restrict__ eW2,
    float* __restrict__ WcT, float* __restrict__ W1T,
    float* __restrict__ Wt0, float* __restrict__ Wt1, float* __restrict__ Wt2) {
    int tid = blockIdx.x * 256 + threadIdx.x;
    int stride = gridDim.x * 256;
    for (int idx = tid; idx < 3 * 464 * 32; idx += stride) {
        int i = idx / (464 * 32); int rem = idx - i * 464 * 32;
        int m = rem >> 5, h = rem & 31;
        float v = 0.f;
        if (m < 456) {
            int seg = m / 152, e = m - seg * 152;
            if (e < 150) v = Wc[((size_t)i * 32 + h) * 450 + seg * 150 + e];
        }
        WcT[idx] = v;
    }
    for (int idx = tid; idx < 456 * 128; idx += stride) {
        int m = idx >> 7, k = idx & 127;
        int seg = m / 152, e = m - seg * 152;
        W1T[idx] = (e < 150) ? W1[k * 450 + seg * 150 + e] : 0.f;
    }
    for (int idx = tid; idx < 304 * 152; idx += stride) {
        int d = idx / 152, e = idx - d * 152;
        Wt0[idx] = (d < 300 && e < 150) ? eW0[e * 300 + d] : 0.f;
    }
    for (int idx = tid; idx < 76 * 152; idx += stride) {
        int d = idx / 152, e = idx - d * 152;
        Wt1[idx] = (d < 74 && e < 150) ? eW1[e * 74 + d] : 0.f;
    }
    for (int idx = tid; idx < 36 * 152; idx += stride) {
        int d = idx / 152, e = idx - d * 152;
        Wt2[idx] = (d < 35 && e < 150) ? eW2[e * 35 + d] : 0.f;
    }
}

// ---------------- K1: fused enc -> attn -> cls. grid 512, block 768, 2 blocks/CU ----------------
__global__ __launch_bounds__(NT, 8) void k_fused(
    const float* __restrict__ x0, const float* __restrict__ x1, const float* __restrict__ x2,
    const float* __restrict__ eb0, const float* __restrict__ eb1, const float* __restrict__ eb2,
    const float* __restrict__ Wt0, const float* __restrict__ Wt1, const float* __restrict__ Wt2,
    const float* __restrict__ WcT,
    const float* __restrict__ affw, const float* __restrict__ Ww, const float* __restrict__ Wh,
    const float* __restrict__ W1T, const float* __restrict__ cb1,
    const float* __restrict__ cW2, const float* __restrict__ cb2,
    float* __restrict__ out, Poly pc) {
    __shared__ __align__(16) float xs[NB * 428];     // x stage
    __shared__ __align__(16) float featf[NB * 468];  // enc outputs; rows 0..3 reused as hs
    __shared__ __align__(16) float fof[NB * 468];    // attn outputs (cls input)
    __shared__ __align__(16) float clsP[3072];       // cls partials: 768 float4
    __shared__ __align__(16) float wWs[96], wHs[96];

    int tid = threadIdx.x;
    int b0 = blockIdx.x * NB;

    // ---- P0: stage x, small weights ----
    if (tid < 96) { wWs[tid] = Ww[tid]; wHs[tid] = Wh[tid]; }
    for (int idx = tid; idx < NB * 75; idx += NT) {
        int b = idx / 75, q = idx - b * 75;
        ((float4*)(xs + b * 428))[q] = ((const float4*)(x0 + (size_t)(b0 + b) * 300))[q];
    }
    for (int idx = tid; idx < NB * 74; idx += NT) {
        int b = idx / 74, d = idx - b * 74;
        xs[b * 428 + 304 + d] = x1[(size_t)(b0 + b) * 74 + d];
    }
    for (int idx = tid; idx < NB * 35; idx += NT) {
        int b = idx / 35, d = idx - b * 35;
        xs[b * 428 + 380 + d] = x2[(size_t)(b0 + b) * 35 + d];
    }
    __syncthreads();

    // ---- P1: encoders. 456 tasks (m4, b), 8-lane-ish W broadcast via b in low bits ----
    if (tid < 456) {
        int m4 = tid >> 2, b = tid & 3;
        int seg = (m4 >= 76) ? 2 : (m4 >= 38) ? 1 : 0;
        int e4 = m4 - seg * 38;
        const float* eb = seg == 0 ? eb0 : seg == 1 ? eb1 : eb2;
        const float4* Wt4 = (const float4*)(seg == 0 ? Wt0 : seg == 1 ? Wt1 : Wt2) + e4;
        const float4* xr = (const float4*)(xs + b * 428 + (seg == 0 ? 0 : seg == 1 ? 304 : 380));
        int DP4 = seg == 0 ? 76 : seg == 1 ? 19 : 9;
        int e = e4 * 4;
        float4 acc;
        acc.x = (e     < 150) ? eb[e]     : 0.f;
        acc.y = (e + 1 < 150) ? eb[e + 1] : 0.f;
        acc.z = (e + 2 < 150) ? eb[e + 2] : 0.f;
        acc.w = (e + 3 < 150) ? eb[e + 3] : 0.f;
        for (int d4 = 0; d4 < DP4; ++d4) {
            float4 x4 = xr[d4];
            float4 w0 = Wt4[(d4 * 4 + 0) * 38];
            float4 w1 = Wt4[(d4 * 4 + 1) * 38];
            float4 w2 = Wt4[(d4 * 4 + 2) * 38];
            float4 w3 = Wt4[(d4 * 4 + 3) * 38];
            FMA4(acc, x4.x, w0);
            FMA4(acc, x4.y, w1);
            FMA4(acc, x4.z, w2);
            FMA4(acc, x4.w, w3);
        }
        ((float4*)(featf + b * 468))[m4] = acc;
    }
    __syncthreads();

    // ---- P2: attention. wave w = (i = w>>2, b = w&3); lane = hq(3b) | slice(3b) ----
    {
        int w = tid >> 6;
        int i = w >> 2, b = w & 3;
        int lane = tid & 63;
        int hq = lane & 7, slice = lane >> 3;   // 8 slices x 57 c
        float aff = affw[i];
        const float4* Wb4 = (const float4*)WcT + (size_t)i * 3712 + hq;
        const float* fb = featf + b * 468;
        const float4* frow = (const float4*)fb;

        float4 acc[NJ];
        #pragma unroll
        for (int J = 0; J < NJ; ++J) acc[J] = make_float4(0.f, 0.f, 0.f, 0.f);
        float mx = 0.f;

        int clo = slice * 57;
        #pragma unroll 3
        for (int k = 0; k < 57; ++k) {
            int c = clo + k;
            float fv = fb[c];
            float4 wv = Wb4[(size_t)c * 8];
            mx = fmaxf(mx, fabsf(fv));
            float g = aff * fv, g2 = g * g;
            float p = g;
            FMA4(acc[0], p, wv);
            #pragma unroll
            for (int J = 1; J < NJ; ++J) { p *= g2; FMA4(acc[J], p, wv); }
        }
        // reduce partial M across slice bits (8,16,32), fold poly coeff
        #pragma unroll
        for (int J = 0; J < NJ; ++J) {
            float cJ = pc.c[J];
            float vx = acc[J].x; vx += __shfl_xor(vx, 8); vx += __shfl_xor(vx, 16); vx += __shfl_xor(vx, 32);
            float vy = acc[J].y; vy += __shfl_xor(vy, 8); vy += __shfl_xor(vy, 16); vy += __shfl_xor(vy, 32);
            float vz = acc[J].z; vz += __shfl_xor(vz, 8); vz += __shfl_xor(vz, 16); vz += __shfl_xor(vz, 32);
            float vw = acc[J].w; vw += __shfl_xor(vw, 8); vw += __shfl_xor(vw, 16); vw += __shfl_xor(vw, 32);
            acc[J].x = vx * cJ; acc[J].y = vy * cJ; acc[J].z = vz * cJ; acc[J].w = vw * cJ;
        }
        // full-row max for fallback guard
        mx = fmaxf(mx, __shfl_xor(mx, 8));
        mx = fmaxf(mx, __shfl_xor(mx, 16));
        mx = fmaxf(mx, __shfl_xor(mx, 32));
        float gmax = fabsf(aff) * mx;

        // epilogue: slices 0..5 -> 5 e4 each, slices 6,7 -> 4 e4
        float4 wW4 = ((const float4*)wWs)[i * 8 + hq];
        float4 wH4 = ((const float4*)wHs)[i * 8 + hq];
        int e4lo = (slice < 6) ? slice * 5 : 30 + (slice - 6) * 4;
        int e4n  = (slice < 6) ? 5 : 4;
        for (int t = 0; t < e4n; ++t) {
            int e4 = e4lo + t;
            float4 s4 = frow[i * 38 + e4];
            float ores[4];
            #pragma unroll
            for (int r = 0; r < 4; ++r) {
                float s = (r == 0) ? s4.x : (r == 1) ? s4.y : (r == 2) ? s4.z : s4.w;
                float4 a4;
                if (fabsf(s) * gmax <= X0f) {
                    float s2 = s * s, p = s;
                    a4.x = acc[0].x * p; a4.y = acc[0].y * p;
                    a4.z = acc[0].z * p; a4.w = acc[0].w * p;
                    #pragma unroll
                    for (int J = 1; J < NJ; ++J) { p *= s2; FMA4(a4, p, acc[J]); }
                } else {
                    a4 = make_float4(0.f, 0.f, 0.f, 0.f);
                    for (int c = 0; c < 456; ++c) {
                        float t2 = tanhf(s * aff * fb[c]);
                        float4 wv = Wb4[(size_t)c * 8];
                        FMA4(a4, t2, wv);
                    }
                }
                float hx = fmaxf(fmaf(s, wW4.x, a4.x), 0.f);
                float hy = fmaxf(fmaf(s, wW4.y, a4.y), 0.f);
                float hz = fmaxf(fmaf(s, wW4.z, a4.z), 0.f);
                float hw = fmaxf(fmaf(s, wW4.w, a4.w), 0.f);
                float csum = hx * wH4.x + hy * wH4.y + hz * wH4.z + hw * wH4.w;
                csum += __shfl_xor(csum, 1);
                csum += __shfl_xor(csum, 2);
                csum += __shfl_xor(csum, 4);
                ores[r] = csum + s;
            }
            if (hq == 0)
                ((float4*)(fof + b * 468))[i * 38 + e4] = make_float4(ores[0], ores[1], ores[2], ores[3]);
        }
    }
    __syncthreads();

    // ---- P3a: classifier stage 1. 768 tasks = (k4 32) x (b 4) x (cs 6), 76 c each ----
    {
        int cs = tid % 6;
        int rr = tid / 6;          // 0..127
        int b = rr & 3, k4 = rr >> 2;
        const float4* W14 = (const float4*)W1T + k4;
        const float4* fr = (const float4*)(fof + b * 468);
        float4 a = make_float4(0.f, 0.f, 0.f, 0.f);
        int c4lo = cs * 19;
        for (int c4 = c4lo; c4 < c4lo + 19; ++c4) {
            float4 fv = fr[c4];
            float4 w0 = W14[(c4 * 4 + 0) * 32];
            float4 w1 = W14[(c4 * 4 + 1) * 32];
            float4 w2 = W14[(c4 * 4 + 2) * 32];
            float4 w3 = W14[(c4 * 4 + 3) * 32];
            FMA4(a, fv.x, w0);
            FMA4(a, fv.y, w1);
            FMA4(a, fv.z, w2);
            FMA4(a, fv.w, w3);
        }
        ((float4*)clsP)[(((size_t)k4 * 4 + b) * 6 + cs)] = a;
    }
    __syncthreads();
    if (tid < 128) {
        int k4 = tid >> 2, b = tid & 3;
        const float4* P = (const float4*)clsP + (k4 * 4 + b) * 6;
        float4 v = ((const float4*)cb1)[k4];
        #pragma unroll
        for (int cs = 0; cs < 6; ++cs) {
            float4 p = P[cs];
            v.x += p.x; v.y += p.y; v.z += p.z; v.w += p.w;
        }
        ((float4*)(featf + b * 468))[k4] = v;   // feat row reused as hs[128]
    }
    __syncthreads();
    if (tid < NB * 7) {
        int b = tid / 7, o = tid - (tid / 7) * 7;
        const float* hb = featf + b * 468;
        const float* w2 = cW2 + o * 128;
        float acc = cb2[o];
        #pragma unroll 4
        for (int k = 0; k < 128; ++k) acc = fmaf(hb[k], w2[k], acc);
        out[(size_t)(b0 + b) * 7 + o] = acc;
    }
}

// ---------------- host: Chebyshev fit of tanh on [-3,3], odd monomials ----------------
static void make_poly(float* cf) {
    const double a = 3.0;
    const int NQ = 128;
    const double PI = 3.14159265358979323846;
    double b[DEG + 1];
    for (int k = 0; k <= DEG; ++k) b[k] = 0.0;
    for (int m = 0; m < NQ; ++m) {
        double th = PI * (m + 0.5) / NQ;
        double f = tanh(a * cos(th));
        for (int k = 1; k <= DEG; k += 2)
            b[k] += (2.0 / NQ) * f * cos(k * th);
    }
    double Tp[DEG + 1], Tc[DEG + 1], Tn[DEG + 1], mono[DEG + 1];
    for (int j = 0; j <= DEG; ++j) { Tp[j] = 0; Tc[j] = 0; mono[j] = 0; }
    Tp[0] = 1.0;
    Tc[1] = 1.0;
    for (int j = 0; j <= DEG; ++j) mono[j] += b[1] * Tc[j];
    for (int k = 2; k <= DEG; ++k) {
        for (int j = 0; j <= DEG; ++j) Tn[j] = -Tp[j];
        for (int j = 1; j <= DEG; ++j) Tn[j] += 2.0 * Tc[j - 1];
        for (int j = 0; j <= DEG; ++j) { Tp[j] = Tc[j]; Tc[j] = Tn[j]; }
        if (k & 1) for (int j = 0; j <= DEG; ++j) mono[j] += b[k] * Tc[j];
    }
    for (int J = 0; J < NJ; ++J) {
        int j = 2 * J + 1;
        cf[J] = (float)(mono[j] / pow(a, (double)j));
    }
}

extern "C" void kernel_launch(void* const* d_in, const int* in_sizes, int n_in,
                              void* d_out, int out_size, void* d_ws, size_t ws_size,
                              hipStream_t stream) {
    (void)in_sizes; (void)n_in; (void)out_size; (void)ws_size;
    const float* x0    = (const float*)d_in[0];
    const float* x1    = (const float*)d_in[1];
    const float* x2    = (const float*)d_in[2];
    const float* eW0   = (const float*)d_in[3];
    const float* eb0   = (const float*)d_in[4];
    const float* eW1   = (const float*)d_in[5];
    const float* eb1   = (const float*)d_in[6];
    const float* eW2   = (const float*)d_in[7];
    const float* eb2   = (const float*)d_in[8];
    const float* affw  = (const float*)d_in[9];
    const float* Ww    = (const float*)d_in[10];
    const float* Wc    = (const float*)d_in[11];
    const float* Wh    = (const float*)d_in[12];
    const float* cW1   = (const float*)d_in[13];
    const float* cb1   = (const float*)d_in[14];
    const float* cW2   = (const float*)d_in[15];
    const float* cb2   = (const float*)d_in[16];

    float* ws    = (float*)d_ws;
    float* wsWcT = ws;                 // 3*464*32  = 44544
    float* wsW1T = ws + 44544;         // 456*128   = 58368
    float* wsWt0 = ws + 102912;        // 304*152   = 46208
    float* wsWt1 = ws + 149120;        // 76*152    = 11552
    float* wsWt2 = ws + 160672;        // 36*152    = 5472

    Poly pc;
    make_poly(pc.c);

    k_repack<<<dim3(96), dim3(256), 0, stream>>>(Wc, cW1, eW0, eW1, eW2,
                                                 wsWcT, wsW1T, wsWt0, wsWt1, wsWt2);
    k_fused<<<dim3(512), dim3(NT), 0, stream>>>(x0, x1, x2, eb0, eb1, eb2,
                                                wsWt0, wsWt1, wsWt2, wsWcT,
                                                affw, Ww, Wh, wsW1T, cb1, cW2, cb2,
                                                (float*)d_out, pc);
}

// Round 10
// 67.294 us; speedup vs baseline: 1.7685x; 1.7685x over previous
//
#include <hip/hip_runtime.h>
#include <math.h>

#define NJ 5         // odd powers x^1..x^9
#define DEG 9
#define X0f 1.25f    // poly valid on [-1.25,1.25]; data range |s*g| <~ 0.5
#define NB 8         // batch rows per block
#define NT 768       // threads per block (12 waves)

struct Poly { float c[NJ]; };

#define FMA4(A,S,W) do { (A).x = fmaf((S),(W).x,(A).x); (A).y = fmaf((S),(W).y,(A).y); \
                         (A).z = fmaf((S),(W).z,(A).z); (A).w = fmaf((S),(W).w,(A).w); } while(0)

// ---------------- K0: repack weights ----------------
__global__ __launch_bounds__(256) void k_repack(
    const float* __restrict__ Wc, const float* __restrict__ W1,
    const float* __restrict__ eW0, const float* __restrict__ eW1, const float* __restrict__ eW2,
    float* __restrict__ WcT, float* __restrict__ W1T,
    float* __restrict__ Wt0, float* __restrict__ Wt1, float* __restrict__ Wt2) {
    int tid = blockIdx.x * 256 + threadIdx.x;
    int stride = gridDim.x * 256;
    for (int idx = tid; idx < 3 * 464 * 32; idx += stride) {
        int i = idx / (464 * 32); int rem = idx - i * 464 * 32;
        int m = rem >> 5, h = rem & 31;
        float v = 0.f;
        if (m < 456) {
            int seg = m / 152, e = m - seg * 152;
            if (e < 150) v = Wc[((size_t)i * 32 + h) * 450 + seg * 150 + e];
        }
        WcT[idx] = v;
    }
    for (int idx = tid; idx < 456 * 128; idx += stride) {
        int m = idx >> 7, k = idx & 127;
        int seg = m / 152, e = m - seg * 152;
        W1T[idx] = (e < 150) ? W1[k * 450 + seg * 150 + e] : 0.f;
    }
    for (int idx = tid; idx < 304 * 152; idx += stride) {
        int d = idx / 152, e = idx - d * 152;
        Wt0[idx] = (d < 300 && e < 150) ? eW0[e * 300 + d] : 0.f;
    }
    for (int idx = tid; idx < 76 * 152; idx += stride) {
        int d = idx / 152, e = idx - d * 152;
        Wt1[idx] = (d < 74 && e < 150) ? eW1[e * 74 + d] : 0.f;
    }
    for (int idx = tid; idx < 36 * 152; idx += stride) {
        int d = idx / 152, e = idx - d * 152;
        Wt2[idx] = (d < 35 && e < 150) ? eW2[e * 35 + d] : 0.f;
    }
}

// ---------------- K1: fully fused enc -> attn -> cls. grid 256, block 768 ----------------
__global__ __launch_bounds__(NT, 1) void k_fused(
    const float* __restrict__ x0, const float* __restrict__ x1, const float* __restrict__ x2,
    const float* __restrict__ eb0, const float* __restrict__ eb1, const float* __restrict__ eb2,
    const float* __restrict__ Wt0, const float* __restrict__ Wt1, const float* __restrict__ Wt2,
    const float* __restrict__ WcT,
    const float* __restrict__ affw, const float* __restrict__ Ww, const float* __restrict__ Wh,
    const float* __restrict__ W1T, const float* __restrict__ cb1,
    const float* __restrict__ cW2, const float* __restrict__ cb2,
    float* __restrict__ out, Poly pc) {
    __shared__ __align__(16) float xs[NB * 428];   // x stage; later cls partial scratch
    __shared__ __align__(16) float featf[NB * 468]; // enc outputs; rows reused as hs
    __shared__ __align__(16) float fof[NB * 468];   // attn outputs (cls input)
    __shared__ __align__(16) float wWs[96], wHs[96];

    int tid = threadIdx.x;
    int b0 = blockIdx.x * NB;

    // ---- P0: stage x, small weights, zero feat pads ----
    if (tid < 96) { wWs[tid] = Ww[tid]; wHs[tid] = Wh[tid]; }
    if (tid >= 96 && tid < 192) {           // zero featf pads 456..467
        int q = tid - 96; int b = q / 12, r = q - b * 12;
        featf[b * 468 + 456 + r] = 0.f;
    }
    if (tid >= 192 && tid < 240) {          // zero fof segment pads (e=150,151)
        int q = tid - 192; int b = q / 6, r = q - b * 6;
        fof[b * 468 + (r >> 1) * 152 + 150 + (r & 1)] = 0.f;
    }
    for (int idx = tid; idx < NB * 75; idx += NT) {
        int b = idx / 75, q = idx - b * 75;
        ((float4*)(xs + b * 428))[q] = ((const float4*)(x0 + (size_t)(b0 + b) * 300))[q];
    }
    for (int idx = tid; idx < NB * 74; idx += NT) {
        int b = idx / 74, d = idx - b * 74;
        xs[b * 428 + 304 + d] = x1[(size_t)(b0 + b) * 74 + d];
    }
    for (int idx = tid; idx < NB * 35; idx += NT) {
        int b = idx / 35, d = idx - b * 35;
        xs[b * 428 + 380 + d] = x2[(size_t)(b0 + b) * 35 + d];
    }
    __syncthreads();

    // ---- P1: encoders. task = (m4 = t>>3, b = t&7): 8-lane W broadcast; 912 tasks ----
    {
        int tasks[2]; int nt = 1;
        tasks[0] = tid;
        if (tid >= 624) { tasks[nt++] = 768 + (767 - tid); }
        for (int q = 0; q < nt; ++q) {
            int task = tasks[q];
            int b = task & 7, m4 = task >> 3;
            int seg = (m4 >= 76) ? 2 : (m4 >= 38) ? 1 : 0;
            int e4 = m4 - seg * 38;
            const float* eb = seg == 0 ? eb0 : seg == 1 ? eb1 : eb2;
            const float4* Wt4 = (const float4*)(seg == 0 ? Wt0 : seg == 1 ? Wt1 : Wt2) + e4;
            const float* xb = xs + b * 428 + (seg == 0 ? 0 : seg == 1 ? 304 : 380);
            int DP4 = seg == 0 ? 76 : seg == 1 ? 19 : 9;
            const float4* xr = (const float4*)xb;
            int e = e4 * 4;
            float4 acc;
            acc.x = (e     < 150) ? eb[e]     : 0.f;
            acc.y = (e + 1 < 150) ? eb[e + 1] : 0.f;
            acc.z = (e + 2 < 150) ? eb[e + 2] : 0.f;
            acc.w = (e + 3 < 150) ? eb[e + 3] : 0.f;
            for (int d4 = 0; d4 < DP4; ++d4) {
                float4 x4 = xr[d4];
                float4 w0 = Wt4[(d4 * 4 + 0) * 38];
                float4 w1 = Wt4[(d4 * 4 + 1) * 38];
                float4 w2 = Wt4[(d4 * 4 + 2) * 38];
                float4 w3 = Wt4[(d4 * 4 + 3) * 38];
                FMA4(acc, x4.x, w0);
                FMA4(acc, x4.y, w1);
                FMA4(acc, x4.z, w2);
                FMA4(acc, x4.w, w3);
            }
            ((float4*)(featf + b * 468))[m4] = acc;
        }
    }
    __syncthreads();

    // ---- P2: attention. wave = (i = w>>2, wp = w&3); lane = hq(3b)|slice(2b)|bh(1b) ----
    {
        int w = tid >> 6;
        int i = w >> 2, wp = w & 3;
        int lane = tid & 63;
        int hq = lane & 7, slice = (lane >> 3) & 3, bh = lane >> 5;
        int b = wp * 2 + bh;
        float aff = affw[i];
        const float4* Wb4 = (const float4*)WcT + (size_t)i * 3712 + hq;
        const float4* frow = (const float4*)(featf + b * 468);

        float4 acc[NJ];
        #pragma unroll
        for (int J = 0; J < NJ; ++J) acc[J] = make_float4(0.f, 0.f, 0.f, 0.f);
        float mx = 0.f;

        int m4lo = slice * 29;
        #pragma unroll 2
        for (int m4 = m4lo; m4 < m4lo + 29; ++m4) {
            float4 f4 = frow[m4];
            const float4* wp4 = Wb4 + m4 * 32;
            float4 w0 = wp4[0];
            float4 w1 = wp4[8];
            float4 w2 = wp4[16];
            float4 w3 = wp4[24];
            mx = fmaxf(mx, fmaxf(fmaxf(fabsf(f4.x), fabsf(f4.y)), fmaxf(fabsf(f4.z), fabsf(f4.w))));
            float g0 = aff * f4.x, g1 = aff * f4.y, g2 = aff * f4.z, g3 = aff * f4.w;
            float q0 = g0 * g0, q1 = g1 * g1, q2 = g2 * g2, q3 = g3 * g3;
            float p0 = g0, p1 = g1, p2 = g2, p3 = g3;
            FMA4(acc[0], p0, w0); FMA4(acc[0], p1, w1); FMA4(acc[0], p2, w2); FMA4(acc[0], p3, w3);
            #pragma unroll
            for (int J = 1; J < NJ; ++J) {
                p0 *= q0; p1 *= q1; p2 *= q2; p3 *= q3;
                FMA4(acc[J], p0, w0); FMA4(acc[J], p1, w1); FMA4(acc[J], p2, w2); FMA4(acc[J], p3, w3);
            }
        }
        // reduce partial M across slice bits (8,16), fold poly coeff
        #pragma unroll
        for (int J = 0; J < NJ; ++J) {
            float cJ = pc.c[J];
            float vx = acc[J].x; vx += __shfl_xor(vx, 8); vx += __shfl_xor(vx, 16);
            float vy = acc[J].y; vy += __shfl_xor(vy, 8); vy += __shfl_xor(vy, 16);
            float vz = acc[J].z; vz += __shfl_xor(vz, 8); vz += __shfl_xor(vz, 16);
            float vw = acc[J].w; vw += __shfl_xor(vw, 8); vw += __shfl_xor(vw, 16);
            acc[J].x = vx * cJ; acc[J].y = vy * cJ; acc[J].z = vz * cJ; acc[J].w = vw * cJ;
        }
        // full-row max for fallback guard
        mx = fmaxf(mx, __shfl_xor(mx, 1));
        mx = fmaxf(mx, __shfl_xor(mx, 2));
        mx = fmaxf(mx, __shfl_xor(mx, 4));
        mx = fmaxf(mx, __shfl_xor(mx, 8));
        mx = fmaxf(mx, __shfl_xor(mx, 16));
        float gmax = fabsf(aff) * mx;

        // epilogue
        float4 wW4 = ((const float4*)wWs)[i * 8 + hq];
        float4 wH4 = ((const float4*)wHs)[i * 8 + hq];
        int e4lo = slice * 10;
        int e4hi = (slice == 3) ? 38 : (e4lo + 10);
        for (int e4 = e4lo; e4 < e4hi; ++e4) {
            float4 s4 = frow[i * 38 + e4];
            float ores[4];
            #pragma unroll
            for (int r = 0; r < 4; ++r) {
                float s = (r == 0) ? s4.x : (r == 1) ? s4.y : (r == 2) ? s4.z : s4.w;
                float4 a4;
                if (fabsf(s) * gmax <= X0f) {
                    float s2 = s * s, p = s;
                    a4.x = acc[0].x * p; a4.y = acc[0].y * p;
                    a4.z = acc[0].z * p; a4.w = acc[0].w * p;
                    #pragma unroll
                    for (int J = 1; J < NJ; ++J) { p *= s2; FMA4(a4, p, acc[J]); }
                } else {
                    a4 = make_float4(0.f, 0.f, 0.f, 0.f);
                    for (int c = 0; c < 456; ++c) {
                        float t = tanhf(s * aff * featf[b * 468 + c]);
                        float4 wv = Wb4[c * 8];
                        FMA4(a4, t, wv);
                    }
                }
                float hx = fmaxf(fmaf(s, wW4.x, a4.x), 0.f);
                float hy = fmaxf(fmaf(s, wW4.y, a4.y), 0.f);
                float hz = fmaxf(fmaf(s, wW4.z, a4.z), 0.f);
                float hw = fmaxf(fmaf(s, wW4.w, a4.w), 0.f);
                float csum = hx * wH4.x + hy * wH4.y + hz * wH4.z + hw * wH4.w;
                csum += __shfl_xor(csum, 1);
                csum += __shfl_xor(csum, 2);
                csum += __shfl_xor(csum, 4);
                ores[r] = csum + s;
            }
            if (hq == 0)
                ((float4*)(fof + b * 468))[i * 38 + e4] = make_float4(ores[0], ores[1], ores[2], ores[3]);
        }
    }
    __syncthreads();

    // ---- P3: classifier stage 1. cs = tid>>8; b = tid&7 (8-lane W broadcast), k4 = (tid>>3)&31 ----
    {
        int cs = tid >> 8;
        int rr = tid & 255;
        int b = rr & 7, k4 = rr >> 3;
        const float4* W14 = (const float4*)W1T + k4;
        const float4* fr = (const float4*)(fof + b * 468);
        float4 a = make_float4(0.f, 0.f, 0.f, 0.f);
        int c4lo = cs * 38;
        for (int c4 = c4lo; c4 < c4lo + 38; ++c4) {
            float4 fv = fr[c4];
            float4 w0 = W14[(c4 * 4 + 0) * 32];
            float4 w1 = W14[(c4 * 4 + 1) * 32];
            float4 w2 = W14[(c4 * 4 + 2) * 32];
            float4 w3 = W14[(c4 * 4 + 3) * 32];
            FMA4(a, fv.x, w0);
            FMA4(a, fv.y, w1);
            FMA4(a, fv.z, w2);
            FMA4(a, fv.w, w3);
        }
        ((float4*)xs)[(cs * 8 + b) * 33 + k4] = a;  // xs reused as hpart
    }
    __syncthreads();
    if (tid < 256) {
        int b = tid >> 5, k4 = tid & 31;
        const float4* hp4 = (const float4*)xs;
        float4 v  = hp4[(0 * 8 + b) * 33 + k4];
        float4 v1 = hp4[(1 * 8 + b) * 33 + k4];
        float4 v2 = hp4[(2 * 8 + b) * 33 + k4];
        float4 bias = ((const float4*)cb1)[k4];
        v.x += v1.x + v2.x + bias.x;
        v.y += v1.y + v2.y + bias.y;
        v.z += v1.z + v2.z + bias.z;
        v.w += v1.w + v2.w + bias.w;
        ((float4*)(featf + b * 468))[k4] = v;  // feat row reused as hs[128]
    }
    __syncthreads();
    if (tid < NB * 7) {
        int b = tid / 7, o = tid - (tid / 7) * 7;
        const float* hb = featf + b * 468;
        const float* w2 = cW2 + o * 128;
        float acc = cb2[o];
        #pragma unroll 4
        for (int k = 0; k < 128; ++k) acc = fmaf(hb[k], w2[k], acc);
        out[(size_t)(b0 + b) * 7 + o] = acc;
    }
}

// ---------------- host: Chebyshev fit of tanh on [-1.25,1.25], odd monomials ----------------
static void make_poly(float* cf) {
    const double a = 1.25;
    const int NQ = 128;
    const double PI = 3.14159265358979323846;
    double b[DEG + 1];
    for (int k = 0; k <= DEG; ++k) b[k] = 0.0;
    for (int m = 0; m < NQ; ++m) {
        double th = PI * (m + 0.5) / NQ;
        double f = tanh(a * cos(th));
        for (int k = 1; k <= DEG; k += 2)
            b[k] += (2.0 / NQ) * f * cos(k * th);
    }
    double Tp[DEG + 1], Tc[DEG + 1], Tn[DEG + 1], mono[DEG + 1];
    for (int j = 0; j <= DEG; ++j) { Tp[j] = 0; Tc[j] = 0; mono[j] = 0; }
    Tp[0] = 1.0;
    Tc[1] = 1.0;
    for (int j = 0; j <= DEG; ++j) mono[j] += b[1] * Tc[j];
    for (int k = 2; k <= DEG; ++k) {
        for (int j = 0; j <= DEG; ++j) Tn[j] = -Tp[j];
        for (int j = 1; j <= DEG; ++j) Tn[j] += 2.0 * Tc[j - 1];
        for (int j = 0; j <= DEG; ++j) { Tp[j] = Tc[j]; Tc[j] = Tn[j]; }
        if (k & 1) for (int j = 0; j <= DEG; ++j) mono[j] += b[k] * Tc[j];
    }
    for (int J = 0; J < NJ; ++J) {
        int j = 2 * J + 1;
        cf[J] = (float)(mono[j] / pow(a, (double)j));
    }
}

extern "C" void kernel_launch(void* const* d_in, const int* in_sizes, int n_in,
                              void* d_out, int out_size, void* d_ws, size_t ws_size,
                              hipStream_t stream) {
    (void)in_sizes; (void)n_in; (void)out_size; (void)ws_size;
    const float* x0    = (const float*)d_in[0];
    const float* x1    = (const float*)d_in[1];
    const float* x2    = (const float*)d_in[2];
    const float* eW0   = (const float*)d_in[3];
    const float* eb0   = (const float*)d_in[4];
    const float* eW1   = (const float*)d_in[5];
    const float* eb1   = (const float*)d_in[6];
    const float* eW2   = (const float*)d_in[7];
    const float* eb2   = (const float*)d_in[8];
    const float* affw  = (const float*)d_in[9];
    const float* Ww    = (const float*)d_in[10];
    const float* Wc    = (const float*)d_in[11];
    const float* Wh    = (const float*)d_in[12];
    const float* cW1   = (const float*)d_in[13];
    const float* cb1   = (const float*)d_in[14];
    const float* cW2   = (const float*)d_in[15];
    const float* cb2   = (const float*)d_in[16];

    float* ws    = (float*)d_ws;
    float* wsWcT = ws;                 // 3*464*32  = 44544
    float* wsW1T = ws + 44544;         // 456*128   = 58368
    float* wsWt0 = ws + 102912;        // 304*152   = 46208
    float* wsWt1 = ws + 149120;        // 76*152    = 11552
    float* wsWt2 = ws + 160672;        // 36*152    = 5472

    Poly pc;
    make_poly(pc.c);

    k_repack<<<dim3(96), dim3(256), 0, stream>>>(Wc, cW1, eW0, eW1, eW2,
                                                 wsWcT, wsW1T, wsWt0, wsWt1, wsWt2);
    k_fused<<<dim3(256), dim3(NT), 0, stream>>>(x0, x1, x2, eb0, eb1, eb2,
                                                wsWt0, wsWt1, wsWt2, wsWcT,
                                                affw, Ww, Wh, wsW1T, cb1, cW2, cb2,
                                                (float*)d_out, pc);
}